// Round 1
// baseline (1593.321 us; speedup 1.0000x reference)
//
#include <hip/hip_runtime.h>

#define N_USERS 100000
#define N_ITEMS 200000
#define N_TOTAL 300000
#define N_EDGES 6000000
#define D 64

// ---------------------------------------------------------------------------
// Kernel 1: trans = all_feat @ W^T + b  (one wave per row), and
//           out   = all_feat           (identity residual init; also clears
//                                       the harness's 0xAA poison)
// W staged in LDS with +1 pad (row stride 65) so the per-lane column read
// Ws[lane][k] spreads across banks instead of a 32-way conflict.
// ---------------------------------------------------------------------------
__global__ __launch_bounds__(256) void linear_residual_kernel(
    const float* __restrict__ user_feat,
    const float* __restrict__ item_feat,
    const float* __restrict__ W,
    const float* __restrict__ b,
    float* __restrict__ trans,
    float* __restrict__ out)
{
    __shared__ float Ws[D][D + 1];
    __shared__ float bs[D];
    const int t = threadIdx.x;
    for (int i = t; i < D * D; i += 256) Ws[i >> 6][i & 63] = W[i];
    if (t < D) bs[t] = b[t];
    __syncthreads();

    const int lane = t & 63;
    const int wib  = t >> 6;                 // wave in block (0..3)
    const int row  = blockIdx.x * 4 + wib;
    if (row >= N_TOTAL) return;

    const float* feat = (row < N_USERS)
        ? user_feat + (size_t)row * D
        : item_feat + (size_t)(row - N_USERS) * D;

    const float fv  = feat[lane];            // lane holds feat[row][lane]
    float acc = bs[lane];
    #pragma unroll
    for (int k = 0; k < D; ++k)
        acc = fmaf(__shfl(fv, k, 64), Ws[lane][k], acc);

    const size_t off = (size_t)row * D + lane;
    trans[off] = acc;
    out[off]   = fv;                         // residual
}

// ---------------------------------------------------------------------------
// Kernel 2: one EDGE per wave; lane j handles column j.
//   out[A_row[e]][j] += A_val[e] * trans[A_col[e]][j]
// Gather + scatter are both 256B contiguous per edge (fully coalesced).
// trans (76.8 MB) is L3-resident -> gathers should mostly hit Infinity Cache.
// ---------------------------------------------------------------------------
__global__ __launch_bounds__(256) void edge_scatter_kernel(
    const int*   __restrict__ A_row,
    const int*   __restrict__ A_col,
    const float* __restrict__ A_val,
    const float* __restrict__ trans,
    float*       __restrict__ out)
{
    const int lane = threadIdx.x & 63;
    const long long e = ((long long)blockIdx.x * 256 + threadIdx.x) >> 6;
    if (e >= N_EDGES) return;

    const int   r = A_row[e];
    const int   c = A_col[e];
    const float v = A_val[e];

    const float m = v * trans[(size_t)c * D + lane];
    atomicAdd(out + (size_t)r * D + lane, m);
}

// ---------------------------------------------------------------------------
// Fallback path (only if ws_size is too small for trans): init residual, then
// recompute the linear transform per edge (avg degree ~20 -> ~49 GFLOP, cheap).
// ---------------------------------------------------------------------------
__global__ __launch_bounds__(256) void init_out_kernel(
    const float* __restrict__ user_feat,
    const float* __restrict__ item_feat,
    float* __restrict__ out)
{
    const size_t i = (size_t)blockIdx.x * 256 + threadIdx.x;
    if (i >= (size_t)N_TOTAL * D) return;
    const size_t urows = (size_t)N_USERS * D;
    out[i] = (i < urows) ? user_feat[i] : item_feat[i - urows];
}

__global__ __launch_bounds__(256) void fused_edge_kernel(
    const int*   __restrict__ A_row,
    const int*   __restrict__ A_col,
    const float* __restrict__ A_val,
    const float* __restrict__ user_feat,
    const float* __restrict__ item_feat,
    const float* __restrict__ W,
    const float* __restrict__ b,
    float*       __restrict__ out)
{
    __shared__ float Ws[D][D + 1];
    __shared__ float bs[D];
    const int t = threadIdx.x;
    for (int i = t; i < D * D; i += 256) Ws[i >> 6][i & 63] = W[i];
    if (t < D) bs[t] = b[t];
    __syncthreads();

    const int lane = t & 63;
    const long long e = ((long long)blockIdx.x * 256 + t) >> 6;
    if (e >= N_EDGES) return;

    const int   r = A_row[e];
    const int   c = A_col[e];
    const float v = A_val[e];

    const float* feat = (c < N_USERS)
        ? user_feat + (size_t)c * D
        : item_feat + (size_t)(c - N_USERS) * D;

    const float fv = feat[lane];
    float acc = bs[lane];
    #pragma unroll
    for (int k = 0; k < D; ++k)
        acc = fmaf(__shfl(fv, k, 64), Ws[lane][k], acc);

    atomicAdd(out + (size_t)r * D + lane, v * acc);
}

// ---------------------------------------------------------------------------
extern "C" void kernel_launch(void* const* d_in, const int* in_sizes, int n_in,
                              void* d_out, int out_size, void* d_ws, size_t ws_size,
                              hipStream_t stream)
{
    const int*   A_row     = (const int*)  d_in[0];
    const int*   A_col     = (const int*)  d_in[1];
    const float* A_val     = (const float*)d_in[2];
    const float* user_feat = (const float*)d_in[3];
    const float* item_feat = (const float*)d_in[4];
    const float* W         = (const float*)d_in[5];
    const float* b         = (const float*)d_in[6];
    float*       out       = (float*)d_out;

    const size_t trans_bytes = (size_t)N_TOTAL * D * sizeof(float);

    if (ws_size >= trans_bytes) {
        float* trans = (float*)d_ws;
        linear_residual_kernel<<<(N_TOTAL + 3) / 4, 256, 0, stream>>>(
            user_feat, item_feat, W, b, trans, out);
        edge_scatter_kernel<<<N_EDGES / 4, 256, 0, stream>>>(
            A_row, A_col, A_val, trans, out);
    } else {
        const size_t total = (size_t)N_TOTAL * D;
        init_out_kernel<<<(int)((total + 255) / 256), 256, 0, stream>>>(
            user_feat, item_feat, out);
        fused_edge_kernel<<<N_EDGES / 4, 256, 0, stream>>>(
            A_row, A_col, A_val, user_feat, item_feat, W, b, out);
    }
}

// Round 2
// 1294.288 us; speedup vs baseline: 1.2310x; 1.2310x over previous
//
#include <hip/hip_runtime.h>

#define N_USERS 100000
#define N_ITEMS 200000
#define N_TOTAL 300000
#define N_EDGES 6000000
#define D 64

#define SCAN_THREADS 256
#define SCAN_ITEMS 4
#define SCAN_TILE (SCAN_THREADS * SCAN_ITEMS)            // 1024
#define SCAN_NBLK ((N_TOTAL + SCAN_TILE - 1) / SCAN_TILE) // 293

// ---------------------------------------------------------------------------
// trans = all_feat @ W^T + b  (one wave per row). If `out` is non-null also
// writes the identity residual (used only by the atomic fallback path).
// W staged in LDS with +1 pad (stride 65) to avoid 32-way bank conflicts.
// ---------------------------------------------------------------------------
__global__ __launch_bounds__(256) void linear_kernel(
    const float* __restrict__ user_feat,
    const float* __restrict__ item_feat,
    const float* __restrict__ W,
    const float* __restrict__ b,
    float* __restrict__ trans,
    float* __restrict__ out)
{
    __shared__ float Ws[D][D + 1];
    __shared__ float bs[D];
    const int t = threadIdx.x;
    for (int i = t; i < D * D; i += 256) Ws[i >> 6][i & 63] = W[i];
    if (t < D) bs[t] = b[t];
    __syncthreads();

    const int lane = t & 63;
    const int row  = blockIdx.x * 4 + (t >> 6);
    if (row >= N_TOTAL) return;

    const float* feat = (row < N_USERS)
        ? user_feat + (size_t)row * D
        : item_feat + (size_t)(row - N_USERS) * D;

    const float fv = feat[lane];
    float acc = bs[lane];
    #pragma unroll
    for (int k = 0; k < D; ++k)
        acc = fmaf(__shfl(fv, k, 64), Ws[lane][k], acc);

    const size_t off = (size_t)row * D + lane;
    trans[off] = acc;
    if (out) out[off] = fv;
}

// ---------------------------------------------------------------------------
// CSR build: histogram -> exclusive scan (3 kernels) -> scatter.
// ---------------------------------------------------------------------------
__global__ __launch_bounds__(256) void hist_kernel(
    const int* __restrict__ A_row, int* __restrict__ rowoff)
{
    const int e = blockIdx.x * 256 + threadIdx.x;
    if (e < N_EDGES) atomicAdd(&rowoff[A_row[e]], 1);
}

__global__ __launch_bounds__(SCAN_THREADS) void scan_block_kernel(
    int* __restrict__ rowoff, int* __restrict__ bsum)
{
    __shared__ int s[SCAN_THREADS];
    const int t    = threadIdx.x;
    const int base = blockIdx.x * SCAN_TILE + t * SCAN_ITEMS;

    int v[SCAN_ITEMS];
    int sum = 0;
    #pragma unroll
    for (int i = 0; i < SCAN_ITEMS; ++i) {
        const int idx = base + i;
        v[i] = (idx < N_TOTAL) ? rowoff[idx] : 0;
        sum += v[i];
    }
    s[t] = sum;
    __syncthreads();
    // Hillis-Steele inclusive scan over 256 thread-sums
    for (int d = 1; d < SCAN_THREADS; d <<= 1) {
        const int x = (t >= d) ? s[t - d] : 0;
        __syncthreads();
        s[t] += x;
        __syncthreads();
    }
    int run = (t == 0) ? 0 : s[t - 1];   // exclusive base for this thread
    #pragma unroll
    for (int i = 0; i < SCAN_ITEMS; ++i) {
        const int idx = base + i;
        if (idx < N_TOTAL) rowoff[idx] = run;   // in-place: v[] already read
        run += v[i];
    }
    if (t == SCAN_THREADS - 1) bsum[blockIdx.x] = s[t];
}

__global__ __launch_bounds__(512) void scan_sums_kernel(int* __restrict__ bsum)
{
    __shared__ int s[512];
    const int t = threadIdx.x;
    s[t] = (t < SCAN_NBLK) ? bsum[t] : 0;
    __syncthreads();
    for (int d = 1; d < 512; d <<= 1) {
        const int x = (t >= d) ? s[t - d] : 0;
        __syncthreads();
        s[t] += x;
        __syncthreads();
    }
    if (t < SCAN_NBLK) bsum[t] = (t == 0) ? 0 : s[t - 1];  // exclusive, in-place
}

__global__ __launch_bounds__(256) void scan_add_kernel(
    int* __restrict__ rowoff, const int* __restrict__ bsum)
{
    const int i = blockIdx.x * 256 + threadIdx.x;
    if (i < N_TOTAL) rowoff[i] += bsum[i / SCAN_TILE];
}

// pos = fetch-and-inc of rowoff[r]; after this kernel rowoff[r] == end of
// row r's segment (== start of row r+1). Pull reads start from rowoff[r-1].
__global__ __launch_bounds__(256) void scatter_kernel(
    const int*   __restrict__ A_row,
    const int*   __restrict__ A_col,
    const float* __restrict__ A_val,
    int*  __restrict__ rowoff,
    int2* __restrict__ epack)
{
    const int e = blockIdx.x * 256 + threadIdx.x;
    if (e >= N_EDGES) return;
    const int r   = A_row[e];
    const int pos = atomicAdd(&rowoff[r], 1);
    epack[pos] = make_int2(A_col[e], __float_as_int(A_val[e]));
}

// ---------------------------------------------------------------------------
// Pull: one wave per destination row, lane = column. No fp32 atomics.
// 2-way unrolled so the two gathers per iteration overlap.
// ---------------------------------------------------------------------------
__global__ __launch_bounds__(256) void pull_kernel(
    const int*   __restrict__ rowoff,
    const int2*  __restrict__ epack,
    const float* __restrict__ trans,
    const float* __restrict__ user_feat,
    const float* __restrict__ item_feat,
    float* __restrict__ out)
{
    const int lane = threadIdx.x & 63;
    const int row  = blockIdx.x * 4 + (threadIdx.x >> 6);
    if (row >= N_TOTAL) return;

    const float* feat = (row < N_USERS)
        ? user_feat + (size_t)row * D
        : item_feat + (size_t)(row - N_USERS) * D;

    float acc0 = feat[lane];          // identity residual
    float acc1 = 0.0f;

    const int s = (row == 0) ? 0 : rowoff[row - 1];
    const int e = rowoff[row];

    int i = s;
    for (; i + 1 < e; i += 2) {
        const int2 p0 = epack[i];
        const int2 p1 = epack[i + 1];
        acc0 = fmaf(__int_as_float(p0.y), trans[(size_t)p0.x * D + lane], acc0);
        acc1 = fmaf(__int_as_float(p1.y), trans[(size_t)p1.x * D + lane], acc1);
    }
    if (i < e) {
        const int2 p = epack[i];
        acc0 = fmaf(__int_as_float(p.y), trans[(size_t)p.x * D + lane], acc0);
    }
    out[(size_t)row * D + lane] = acc0 + acc1;
}

// ---------------------------------------------------------------------------
// Fallback kernels (small workspace): round-1 atomic push path.
// ---------------------------------------------------------------------------
__global__ __launch_bounds__(256) void edge_scatter_kernel(
    const int*   __restrict__ A_row,
    const int*   __restrict__ A_col,
    const float* __restrict__ A_val,
    const float* __restrict__ trans,
    float*       __restrict__ out)
{
    const int lane = threadIdx.x & 63;
    const long long e = ((long long)blockIdx.x * 256 + threadIdx.x) >> 6;
    if (e >= N_EDGES) return;
    const int   r = A_row[e];
    const int   c = A_col[e];
    const float v = A_val[e];
    atomicAdd(out + (size_t)r * D + lane, v * trans[(size_t)c * D + lane]);
}

__global__ __launch_bounds__(256) void init_out_kernel(
    const float* __restrict__ user_feat,
    const float* __restrict__ item_feat,
    float* __restrict__ out)
{
    const size_t i = (size_t)blockIdx.x * 256 + threadIdx.x;
    if (i >= (size_t)N_TOTAL * D) return;
    const size_t urows = (size_t)N_USERS * D;
    out[i] = (i < urows) ? user_feat[i] : item_feat[i - urows];
}

__global__ __launch_bounds__(256) void fused_edge_kernel(
    const int*   __restrict__ A_row,
    const int*   __restrict__ A_col,
    const float* __restrict__ A_val,
    const float* __restrict__ user_feat,
    const float* __restrict__ item_feat,
    const float* __restrict__ W,
    const float* __restrict__ b,
    float*       __restrict__ out)
{
    __shared__ float Ws[D][D + 1];
    __shared__ float bs[D];
    const int t = threadIdx.x;
    for (int i = t; i < D * D; i += 256) Ws[i >> 6][i & 63] = W[i];
    if (t < D) bs[t] = b[t];
    __syncthreads();

    const int lane = t & 63;
    const long long e = ((long long)blockIdx.x * 256 + t) >> 6;
    if (e >= N_EDGES) return;

    const int   r = A_row[e];
    const int   c = A_col[e];
    const float v = A_val[e];

    const float* feat = (c < N_USERS)
        ? user_feat + (size_t)c * D
        : item_feat + (size_t)(c - N_USERS) * D;

    const float fv = feat[lane];
    float acc = bs[lane];
    #pragma unroll
    for (int k = 0; k < D; ++k)
        acc = fmaf(__shfl(fv, k, 64), Ws[lane][k], acc);

    atomicAdd(out + (size_t)r * D + lane, v * acc);
}

// ---------------------------------------------------------------------------
extern "C" void kernel_launch(void* const* d_in, const int* in_sizes, int n_in,
                              void* d_out, int out_size, void* d_ws, size_t ws_size,
                              hipStream_t stream)
{
    const int*   A_row     = (const int*)  d_in[0];
    const int*   A_col     = (const int*)  d_in[1];
    const float* A_val     = (const float*)d_in[2];
    const float* user_feat = (const float*)d_in[3];
    const float* item_feat = (const float*)d_in[4];
    const float* W         = (const float*)d_in[5];
    const float* b         = (const float*)d_in[6];
    float*       out       = (float*)d_out;

    const size_t trans_bytes  = (size_t)N_TOTAL * D * sizeof(float);        // 76.8 MB
    const size_t rowoff_bytes = ((size_t)N_TOTAL * sizeof(int) + 255) & ~(size_t)255;
    const size_t bsum_bytes   = ((size_t)SCAN_NBLK * sizeof(int) + 255) & ~(size_t)255;
    const size_t epack_bytes  = (size_t)N_EDGES * sizeof(int2);             // 48 MB
    const size_t csr_total    = trans_bytes + rowoff_bytes + bsum_bytes + epack_bytes;

    const int edge_blocks = (N_EDGES + 255) / 256;
    const int row_blocks  = (N_TOTAL + 3) / 4;

    if (ws_size >= csr_total) {
        char* p = (char*)d_ws;
        float* trans  = (float*)p;                    p += trans_bytes;
        int*   rowoff = (int*)p;                      p += rowoff_bytes;
        int*   bsum   = (int*)p;                      p += bsum_bytes;
        int2*  epack  = (int2*)p;

        hipMemsetAsync(rowoff, 0, (size_t)N_TOTAL * sizeof(int), stream);
        linear_kernel<<<row_blocks, 256, 0, stream>>>(
            user_feat, item_feat, W, b, trans, nullptr);
        hist_kernel<<<edge_blocks, 256, 0, stream>>>(A_row, rowoff);
        scan_block_kernel<<<SCAN_NBLK, SCAN_THREADS, 0, stream>>>(rowoff, bsum);
        scan_sums_kernel<<<1, 512, 0, stream>>>(bsum);
        scan_add_kernel<<<(N_TOTAL + 255) / 256, 256, 0, stream>>>(rowoff, bsum);
        scatter_kernel<<<edge_blocks, 256, 0, stream>>>(
            A_row, A_col, A_val, rowoff, epack);
        pull_kernel<<<row_blocks, 256, 0, stream>>>(
            rowoff, epack, trans, user_feat, item_feat, out);
    } else if (ws_size >= trans_bytes) {
        float* trans = (float*)d_ws;
        linear_kernel<<<row_blocks, 256, 0, stream>>>(
            user_feat, item_feat, W, b, trans, out);
        edge_scatter_kernel<<<N_EDGES / 4, 256, 0, stream>>>(
            A_row, A_col, A_val, trans, out);
    } else {
        const size_t total = (size_t)N_TOTAL * D;
        init_out_kernel<<<(int)((total + 255) / 256), 256, 0, stream>>>(
            user_feat, item_feat, out);
        fused_edge_kernel<<<N_EDGES / 4, 256, 0, stream>>>(
            A_row, A_col, A_val, user_feat, item_feat, W, b, out);
    }
}